// Round 9
// baseline (166.974 us; speedup 1.0000x reference)
//
#include <hip/hip_runtime.h>

// GNN encoder, B=256, N=32, F=256, fully-connected edges, 2 passes.
// bf16 MFMA 16x16x32, fp32 accum.
// R9: edge v9 — small waves (64x64 tile, acc[4][4]=64 regs) so 4 waves/SIMD
// (4 blocks/CU, independent barrier domains). Block = 2 receivers x 256 cols.
// MLP chains (R8, swapped-operand fusion) unchanged.

typedef short bf16x8 __attribute__((ext_vector_type(8)));
typedef float f32x4 __attribute__((ext_vector_type(4)));
typedef unsigned short ushort_t;

__device__ __forceinline__ unsigned short f2bf(float f) {
    unsigned u = __float_as_uint(f);
    u += 0x7fff + ((u >> 16) & 1);   // RNE
    return (unsigned short)(u >> 16);
}
__device__ __forceinline__ float lo16f(unsigned w) { return __uint_as_float(w << 16); }
__device__ __forceinline__ float hi16f(unsigned w) { return __uint_as_float(w & 0xffff0000u); }
__device__ __forceinline__ unsigned cvt_pk_bf16(float lo, float hi) {
    unsigned r;
    asm volatile("v_cvt_pk_bf16_f32 %0, %1, %2" : "=v"(r) : "v"(lo), "v"(hi));
    return r;
}
__device__ __forceinline__ void gload16(const void* g, void* l) {
    __builtin_amdgcn_global_load_lds(
        (const __attribute__((address_space(1))) void*)g,
        (__attribute__((address_space(3))) void*)l, 16, 0, 0);
}

// ---------------------------------------------------------------------------
// Weight prep: logical Wt[n][k] -> swizzled image:
// idx = kb*8192 + n*32 + (kc ^ ((n>>1)&3))*8 + (k&7), kb=k>>5, kc=(k>>3)&3.
__global__ __launch_bounds__(256) void prep_weights(
    const float* __restrict__ w_in1, const float* __restrict__ w_in2,
    const float* __restrict__ w_e1,  const float* __restrict__ w_e2,
    const float* __restrict__ w_n1,  const float* __restrict__ w_n2,
    ushort_t* __restrict__ dst)
{
    __shared__ ushort_t tile[32][264];
    const int wid = blockIdx.x >> 3;   // 0..6
    const int kb  = blockIdx.x & 7;
    const float* src;
    switch (wid) {
        case 0: src = w_in1; break;
        case 1: src = w_in2; break;
        case 2: src = w_e1; break;              // top half (send side)
        case 3: src = w_e1 + 65536; break;      // bottom half (recv side)
        case 4: src = w_e2; break;
        case 5: src = w_n1; break;
        default: src = w_n2; break;
    }
    const int t = threadIdx.x;
#pragma unroll
    for (int k0 = 0; k0 < 32; k0++)
        tile[k0][t] = f2bf(src[(size_t)(kb * 32 + k0) * 256 + t]);  // coalesced
    __syncthreads();
    ushort_t* base = dst + wid * 65536 + kb * 8192 + t * 32;
    const int sw = (t >> 1) & 3;
#pragma unroll
    for (int kc = 0; kc < 4; kc++) {
        union { uint4 q; ushort_t u[8]; } w;
#pragma unroll
        for (int ko = 0; ko < 8; ko++) w.u[ko] = tile[kc * 8 + ko][t];
        *(uint4*)&base[(kc ^ sw) * 8] = w.q;
    }
}

// x fp32 -> bf16
__global__ __launch_bounds__(256) void conv_x(
    const float* __restrict__ x, ushort_t* __restrict__ xb, int n8)
{
    int i = blockIdx.x * 256 + threadIdx.x;
    if (i >= n8) return;
    const float4* p = (const float4*)x + (size_t)i * 2;
    float4 a = p[0], b = p[1];
    ushort4 o0 = make_ushort4(f2bf(a.x), f2bf(a.y), f2bf(a.z), f2bf(a.w));
    ushort4 o1 = make_ushort4(f2bf(b.x), f2bf(b.y), f2bf(b.z), f2bf(b.w));
    ((ushort4*)xb)[(size_t)i * 2]     = o0;
    ((ushort4*)xb)[(size_t)i * 2 + 1] = o1;
}

// ---------------------------------------------------------------------------
// Fused MLP chain (R8). Block = 32 rows, 4 waves (wave owns a 64-col slice).
// A-tiles [32][256] bf16 in LDS, XOR chunk swizzle: elem off =
//   r*256 + ((kc ^ (r&7))*8) + (k&7), kc = k>>3.
// Swapped MFMA: acc = mfma(Wfrag, Xfrag) -> D[row=n (reg), col=m (lane&15)],
// so each lane holds 4 k-contiguous outputs -> b64 LDS writes for handoff.

__device__ __forceinline__ void layer_to_lds(
    const ushort_t* __restrict__ wimg, const float* __restrict__ bias,
    const ushort_t* __restrict__ As, ushort_t* __restrict__ Ad,
    const int w, const int lr, const int lg)
{
    int boffs[4]; float4 b4[4];
#pragma unroll
    for (int fn = 0; fn < 4; fn++) {
        const int n = w * 64 + fn * 16 + lr;
        boffs[fn] = n * 32 + ((lg ^ ((n >> 1) & 3)) * 8);
        b4[fn] = *(const float4*)&bias[w * 64 + fn * 16 + lg * 4];
    }
    bf16x8 bc[4];
#pragma unroll
    for (int fn = 0; fn < 4; fn++) bc[fn] = *(const bf16x8*)&wimg[boffs[fn]];
    f32x4 acc[4][2] = {};
#pragma unroll
    for (int kb = 0; kb < 8; kb++) {
        bf16x8 bn[4];
        if (kb < 7)
#pragma unroll
            for (int fn = 0; fn < 4; fn++)
                bn[fn] = *(const bf16x8*)&wimg[(kb + 1) * 8192 + boffs[fn]];
        bf16x8 af[2];
#pragma unroll
        for (int fm = 0; fm < 2; fm++) {
            const int r = fm * 16 + lr;
            af[fm] = *(const bf16x8*)&As[r * 256 + (((kb * 4 + lg) ^ (r & 7)) * 8)];
        }
#pragma unroll
        for (int fn = 0; fn < 4; fn++)
#pragma unroll
            for (int fm = 0; fm < 2; fm++)
                acc[fn][fm] = __builtin_amdgcn_mfma_f32_16x16x32_bf16(
                    bc[fn], af[fm], acc[fn][fm], 0, 0, 0);
        if (kb < 7)
#pragma unroll
            for (int fn = 0; fn < 4; fn++) bc[fn] = bn[fn];
    }
#pragma unroll
    for (int fn = 0; fn < 4; fn++) {
        const int k0 = w * 64 + fn * 16 + lg * 4;     // output col = next-layer k
        const int kc = k0 >> 3, kj = k0 & 7;
#pragma unroll
        for (int fm = 0; fm < 2; fm++) {
            const int m = fm * 16 + lr;
            float v0 = fmaxf(acc[fn][fm][0] + b4[fn].x, 0.f);
            float v1 = fmaxf(acc[fn][fm][1] + b4[fn].y, 0.f);
            float v2 = fmaxf(acc[fn][fm][2] + b4[fn].z, 0.f);
            float v3 = fmaxf(acc[fn][fm][3] + b4[fn].w, 0.f);
            uint2 q = { cvt_pk_bf16(v0, v1), cvt_pk_bf16(v2, v3) };
            *(uint2*)&Ad[m * 256 + ((kc ^ (m & 7)) * 8) + kj] = q;
        }
    }
}

__device__ __forceinline__ void layer_e1(
    const ushort_t* __restrict__ wE, const float* __restrict__ bE,
    const ushort_t* __restrict__ As, ushort_t* __restrict__ UVb,
    const int m0, const int w, const int lr, const int lg)
{
    const ushort_t* wimg = (w < 2) ? wE : (wE + 65536);
    const int nb = (w & 1) * 128;
    int boffs[8]; float4 b4[8];
#pragma unroll
    for (int fn = 0; fn < 8; fn++) {
        const int n = nb + fn * 16 + lr;
        boffs[fn] = n * 32 + ((lg ^ ((n >> 1) & 3)) * 8);
        if (w < 2) b4[fn] = *(const float4*)&bE[nb + fn * 16 + lg * 4];
        else       b4[fn] = make_float4(0.f, 0.f, 0.f, 0.f);
    }
    bf16x8 bc[8];
#pragma unroll
    for (int fn = 0; fn < 8; fn++) bc[fn] = *(const bf16x8*)&wimg[boffs[fn]];
    f32x4 acc[8][2] = {};
#pragma unroll
    for (int kb = 0; kb < 8; kb++) {
        bf16x8 bn[8];
        if (kb < 7)
#pragma unroll
            for (int fn = 0; fn < 8; fn++)
                bn[fn] = *(const bf16x8*)&wimg[(kb + 1) * 8192 + boffs[fn]];
        bf16x8 af[2];
#pragma unroll
        for (int fm = 0; fm < 2; fm++) {
            const int r = fm * 16 + lr;
            af[fm] = *(const bf16x8*)&As[r * 256 + (((kb * 4 + lg) ^ (r & 7)) * 8)];
        }
#pragma unroll
        for (int fn = 0; fn < 8; fn++)
#pragma unroll
            for (int fm = 0; fm < 2; fm++)
                acc[fn][fm] = __builtin_amdgcn_mfma_f32_16x16x32_bf16(
                    bc[fn], af[fm], acc[fn][fm], 0, 0, 0);
        if (kb < 7)
#pragma unroll
            for (int fn = 0; fn < 8; fn++) bc[fn] = bn[fn];
    }
#pragma unroll
    for (int fn = 0; fn < 8; fn++) {
        const int nglob = w * 128 + fn * 16 + lg * 4;
#pragma unroll
        for (int fm = 0; fm < 2; fm++) {
            const int node = m0 + fm * 16 + lr;
            float v0 = acc[fn][fm][0] + b4[fn].x;
            float v1 = acc[fn][fm][1] + b4[fn].y;
            float v2 = acc[fn][fm][2] + b4[fn].z;
            float v3 = acc[fn][fm][3] + b4[fn].w;
            uint2 q = { cvt_pk_bf16(v0, v1), cvt_pk_bf16(v2, v3) };
            *(uint2*)&UVb[(size_t)node * 512 + nglob] = q;
        }
    }
}

__device__ __forceinline__ void layer_fin(
    const ushort_t* __restrict__ wimg, const float* __restrict__ bias,
    const ushort_t* __restrict__ As, float* __restrict__ out,
    const int m0, const int w, const int lr, const int lg)
{
    int boffs[4]; float4 b4[4];
#pragma unroll
    for (int fn = 0; fn < 4; fn++) {
        const int n = w * 64 + fn * 16 + lr;
        boffs[fn] = n * 32 + ((lg ^ ((n >> 1) & 3)) * 8);
        b4[fn] = *(const float4*)&bias[w * 64 + fn * 16 + lg * 4];
    }
    bf16x8 bc[4];
#pragma unroll
    for (int fn = 0; fn < 4; fn++) bc[fn] = *(const bf16x8*)&wimg[boffs[fn]];
    f32x4 acc[4][2] = {};
#pragma unroll
    for (int kb = 0; kb < 8; kb++) {
        bf16x8 bn[4];
        if (kb < 7)
#pragma unroll
            for (int fn = 0; fn < 4; fn++)
                bn[fn] = *(const bf16x8*)&wimg[(kb + 1) * 8192 + boffs[fn]];
        bf16x8 af[2];
#pragma unroll
        for (int fm = 0; fm < 2; fm++) {
            const int r = fm * 16 + lr;
            af[fm] = *(const bf16x8*)&As[r * 256 + (((kb * 4 + lg) ^ (r & 7)) * 8)];
        }
#pragma unroll
        for (int fn = 0; fn < 4; fn++)
#pragma unroll
            for (int fm = 0; fm < 2; fm++)
                acc[fn][fm] = __builtin_amdgcn_mfma_f32_16x16x32_bf16(
                    bc[fn], af[fm], acc[fn][fm], 0, 0, 0);
        if (kb < 7)
#pragma unroll
            for (int fn = 0; fn < 4; fn++) bc[fn] = bn[fn];
    }
#pragma unroll
    for (int fn = 0; fn < 4; fn++) {
        const int col = w * 64 + fn * 16 + lg * 4;
#pragma unroll
        for (int fm = 0; fm < 2; fm++) {
            const int row = m0 + fm * 16 + lr;
            float4 o;
            o.x = fmaxf(acc[fn][fm][0] + b4[fn].x, 0.f);
            o.y = fmaxf(acc[fn][fm][1] + b4[fn].y, 0.f);
            o.z = fmaxf(acc[fn][fm][2] + b4[fn].z, 0.f);
            o.w = fmaxf(acc[fn][fm][3] + b4[fn].w, 0.f);
            *(float4*)&out[(size_t)row * 256 + col] = o;
        }
    }
}

template <int THREE>
__global__ __launch_bounds__(256, 2) void mlp_chain(
    const ushort_t* __restrict__ in,
    const ushort_t* __restrict__ wA, const float* __restrict__ bA,
    const ushort_t* __restrict__ wB, const float* __restrict__ bB,
    const ushort_t* __restrict__ wE, const float* __restrict__ bE,
    void* __restrict__ out)
{
    __shared__ ushort_t A0[32 * 256];
    __shared__ ushort_t A1[32 * 256];
    const int m0 = blockIdx.x * 32;
    const int t = threadIdx.x;
    const int lane = t & 63, w = t >> 6;
    const int lr = lane & 15, lg = lane >> 4;

#pragma unroll
    for (int i = 0; i < 4; i++) {
        const int r = i * 8 + (t >> 5);
        const int p = t & 31;
        gload16(in + (size_t)(m0 + r) * 256 + ((p ^ (r & 7)) * 8), &A0[i * 2048 + t * 8]);
    }
    __syncthreads();

    layer_to_lds(wA, bA, A0, A1, w, lr, lg);
    __syncthreads();
    if constexpr (THREE) {
        layer_to_lds(wB, bB, A1, A0, w, lr, lg);
        __syncthreads();
        layer_e1(wE, bE, A0, (ushort_t*)out, m0, w, lr, lg);
    } else {
        layer_fin(wB, bB, A1, (float*)out, m0, w, lr, lg);
    }
}

// ---------------------------------------------------------------------------
// Fused edge layer-2 + scatter-mean, v9: small waves for occupancy.
// Grid 4096 x 256 thr (4 waves). Block = (batch, PAIR of receivers):
// M = 64 virtual rows (2 recv x 32 slots, slot31 dummy) x N=256.
// Wave w owns cols [w*64, w*64+64): wave tile 64x64, acc[4][4] (64 regs).
// A = relu(U'[send]+V[recv]) built into 1-barrier LDS dbuf; B-frags
// streamed from the L2-resident swizzled w_e2 image, prefetched 1 step ahead.
// __launch_bounds__(256,4): 4 blocks/CU -> 4 waves/SIMD, desynced barriers.
__global__ __launch_bounds__(256, 4) void edge_fused(
    const ushort_t* __restrict__ UVb,   // [8192][512] bf16: U'(+b_e1) | V
    const ushort_t* __restrict__ WBsw,  // swizzled w_e2 image
    const float* __restrict__ b2,
    ushort_t* __restrict__ agg)         // [8192][256] bf16
{
    __shared__ ushort_t As[2][2048];    // 64 rows x 32 k each

    const int logical = (blockIdx.x & 7) * 512 + (blockIdx.x >> 3);  // 4096%8==0
    const int bb = logical >> 4;        // batch
    const int p0 = (logical & 15) * 2;  // first receiver of the pair
    const int t = threadIdx.x;
    const int lane = t & 63;
    const int w = t >> 6;
    const int lr = lane & 15, lg = lane >> 4;

    // ---- A-build mapping: thread -> (row, chunk). 4 threads per row.
    const int brow = t >> 2;            // 0..63
    const int ck = t & 3;
    const int jr = brow >> 5;           // receiver within pair
    const int s = brow & 31;            // slot
    const int j = p0 + jr;
    const int si = (s == 31) ? j : (s + (s >= j ? 1 : 0));
    const ushort_t* up = UVb + (size_t)(bb * 32 + si) * 512 + ck * 8;
    const ushort_t* vp = UVb + (size_t)(bb * 32 + j) * 512 + 256 + ck * 8;
    const int aw = brow * 32 + ((ck ^ ((brow >> 1) & 3)) * 8);

    // ---- MFMA-side bases; swizzle term (r>>1)&3 == (lr>>1)&3 (f-independent)
    const int asw = (lg ^ ((lr >> 1) & 3)) * 8;
    const int abase = lr * 32 + asw;                 // + f*512
    const int bbase = (w * 64 + lr) * 32 + asw;      // + fn*512

    // ---- prologue: build k-tile 0, load B k-tile 0
    {
        uint4 u = *(const uint4*)up;
        uint4 v = *(const uint4*)vp;
        uint4 q;
        q.x = cvt_pk_bf16(fmaxf(lo16f(u.x) + lo16f(v.x), 0.f), fmaxf(hi16f(u.x) + hi16f(v.x), 0.f));
        q.y = cvt_pk_bf16(fmaxf(lo16f(u.y) + lo16f(v.y), 0.f), fmaxf(hi16f(u.y) + hi16f(v.y), 0.f));
        q.z = cvt_pk_bf16(fmaxf(lo16f(u.z) + lo16f(v.z), 0.f), fmaxf(hi16f(u.z) + hi16f(v.z), 0.f));
        q.w = cvt_pk_bf16(fmaxf(lo16f(u.w) + lo16f(v.w), 0.f), fmaxf(hi16f(u.w) + hi16f(v.w), 0.f));
        *(uint4*)&As[0][aw] = q;
    }
    bf16x8 bc[4];
#pragma unroll
    for (int fn = 0; fn < 4; fn++) bc[fn] = *(const bf16x8*)&WBsw[bbase + fn * 512];

    f32x4 acc[4][4] = {};

#pragma unroll
    for (int kb = 0; kb < 8; kb++) {
        __syncthreads();                      // As[kb&1] ready
        // prefetch next-step inputs (hidden under this step's MFMAs)
        uint4 u, v;
        bf16x8 bn[4];
        if (kb < 7) {
            u = *(const uint4*)(up + (kb + 1) * 32);
            v = *(const uint4*)(vp + (kb + 1) * 32);
#pragma unroll
            for (int fn = 0; fn < 4; fn++)
                bn[fn] = *(const bf16x8*)&WBsw[(kb + 1) * 8192 + bbase + fn * 512];
        }
        // MFMA on current tile
        bf16x8 af[4];
#pragma unroll
        for (int f = 0; f < 4; f++) af[f] = *(const bf16x8*)&As[kb & 1][abase + f * 512];
        __builtin_amdgcn_s_setprio(1);
#pragma unroll
        for (int fn = 0; fn < 4; fn++)
#pragma unroll
            for (int m = 0; m < 4; m++)
                acc[m][fn] = __builtin_amdgcn_mfma_f32_16x16x32_bf16(
                    af[m], bc[fn], acc[m][fn], 0, 0, 0);
        __builtin_amdgcn_s_setprio(0);
        // build next tile + rotate B
        if (kb < 7) {
            uint4 q;
            q.x = cvt_pk_bf16(fmaxf(lo16f(u.x) + lo16f(v.x), 0.f), fmaxf(hi16f(u.x) + hi16f(v.x), 0.f));
            q.y = cvt_pk_bf16(fmaxf(lo16f(u.y) + lo16f(v.y), 0.f), fmaxf(hi16f(u.y) + hi16f(v.y), 0.f));
            q.z = cvt_pk_bf16(fmaxf(lo16f(u.z) + lo16f(v.z), 0.f), fmaxf(hi16f(u.z) + hi16f(v.z), 0.f));
            q.w = cvt_pk_bf16(fmaxf(lo16f(u.w) + lo16f(v.w), 0.f), fmaxf(hi16f(u.w) + hi16f(v.w), 0.f));
            *(uint4*)&As[(kb + 1) & 1][aw] = q;
#pragma unroll
            for (int fn = 0; fn < 4; fn++) bc[fn] = bn[fn];
        }
    }

    // ---- Epilogue: bias+relu, sum 31 real slots per receiver, /31, bf16 out.
#pragma unroll
    for (int fn = 0; fn < 4; fn++) {
        const int col = w * 64 + fn * 16 + lr;
        const float bvf = b2[col];
#pragma unroll
        for (int h = 0; h < 2; h++) {         // receiver within pair
            float sum = 0.f;
#pragma unroll
            for (int q = 0; q < 2; q++) {
                const int fm = 2 * h + q;
#pragma unroll
                for (int r = 0; r < 4; r++) {
                    float v = fmaxf(acc[fm][fn][r] + bvf, 0.f);
                    if (!(q == 1 && lg == 3 && r == 3)) sum += v;  // skip slot 31
                }
            }
            sum += __shfl_xor(sum, 16);
            sum += __shfl_xor(sum, 32);
            if (lane < 16)
                agg[(size_t)(bb * 32 + p0 + h) * 256 + col] = f2bf(sum * (1.0f / 31.0f));
        }
    }
}

// ---------------------------------------------------------------------------
extern "C" void kernel_launch(void* const* d_in, const int* in_sizes, int n_in,
                              void* d_out, int out_size, void* d_ws, size_t ws_size,
                              hipStream_t stream)
{
    const float* x     = (const float*)d_in[0];
    const float* w_in1 = (const float*)d_in[3];
    const float* b_in1 = (const float*)d_in[4];
    const float* w_in2 = (const float*)d_in[5];
    const float* b_in2 = (const float*)d_in[6];
    const float* w_e1  = (const float*)d_in[7];
    const float* b_e1  = (const float*)d_in[8];
    const float* w_e2  = (const float*)d_in[9];
    const float* b_e2  = (const float*)d_in[10];
    const float* w_n1  = (const float*)d_in[11];
    const float* b_n1  = (const float*)d_in[12];
    const float* w_n2  = (const float*)d_in[13];
    const float* b_n2  = (const float*)d_in[14];

    char* ws = (char*)d_ws;
    size_t off = 0;
    auto alloc = [&](size_t n) { char* p = ws + off; off += (n + 255) & ~(size_t)255; return p; };

    ushort_t* wt  = (ushort_t*)alloc(7 * 65536 * sizeof(ushort_t));
    ushort_t* xb  = (ushort_t*)alloc(8192 * 256 * 2);
    ushort_t* UVb = (ushort_t*)alloc(8192 * 512 * 2);
    ushort_t* ag  = (ushort_t*)alloc(8192 * 256 * 2);
    (void)ws_size; (void)in_sizes; (void)n_in; (void)out_size;

    prep_weights<<<56, 256, 0, stream>>>(w_in1, w_in2, w_e1, w_e2, w_n1, w_n2, wt);
    conv_x<<<1024, 256, 0, stream>>>(x, xb, 262144);

    // pass 0 front: in1 -> in2 -> e1
    mlp_chain<1><<<256, 256, 0, stream>>>(xb,
        wt + 0 * 65536, b_in1, wt + 1 * 65536, b_in2, wt + 2 * 65536, b_e1, UVb);
    edge_fused<<<4096, 256, 0, stream>>>(UVb, wt + 4 * 65536, b_e2, ag);
    // pass 1 front: n1 -> n2 -> e1
    mlp_chain<1><<<256, 256, 0, stream>>>(ag,
        wt + 5 * 65536, b_n1, wt + 6 * 65536, b_n2, wt + 2 * 65536, b_e1, UVb);
    edge_fused<<<4096, 256, 0, stream>>>(UVb, wt + 4 * 65536, b_e2, ag);
    // final: n1 -> n2 (f32 out)
    mlp_chain<0><<<256, 256, 0, stream>>>(ag,
        wt + 5 * 65536, b_n1, wt + 6 * 65536, b_n2, nullptr, nullptr, d_out);
}

// Round 10
// 134.182 us; speedup vs baseline: 1.2444x; 1.2444x over previous
//
#include <hip/hip_runtime.h>

// GNN encoder, B=256, N=32, F=256, fully-connected edges, 2 passes.
// bf16 MFMA 16x16x32, fp32 accum.
// R10: edge v10 = R8's v7 structure (128 rows x 256 cols, 4 waves, 2048 blocks)
// with BK=64 K-steps (4 barriers, 64-MFMA streaks). MLP chains (R8) unchanged.

typedef short bf16x8 __attribute__((ext_vector_type(8)));
typedef float f32x4 __attribute__((ext_vector_type(4)));
typedef unsigned short ushort_t;

__device__ __forceinline__ unsigned short f2bf(float f) {
    unsigned u = __float_as_uint(f);
    u += 0x7fff + ((u >> 16) & 1);   // RNE
    return (unsigned short)(u >> 16);
}
__device__ __forceinline__ float lo16f(unsigned w) { return __uint_as_float(w << 16); }
__device__ __forceinline__ float hi16f(unsigned w) { return __uint_as_float(w & 0xffff0000u); }
__device__ __forceinline__ unsigned cvt_pk_bf16(float lo, float hi) {
    unsigned r;
    asm volatile("v_cvt_pk_bf16_f32 %0, %1, %2" : "=v"(r) : "v"(lo), "v"(hi));
    return r;
}
__device__ __forceinline__ void gload16(const void* g, void* l) {
    __builtin_amdgcn_global_load_lds(
        (const __attribute__((address_space(1))) void*)g,
        (__attribute__((address_space(3))) void*)l, 16, 0, 0);
}

// ---------------------------------------------------------------------------
// Weight prep: logical Wt[n][k] -> swizzled image:
// idx = kb*8192 + n*32 + (kc ^ ((n>>1)&3))*8 + (k&7), kb=k>>5, kc=(k>>3)&3.
__global__ __launch_bounds__(256) void prep_weights(
    const float* __restrict__ w_in1, const float* __restrict__ w_in2,
    const float* __restrict__ w_e1,  const float* __restrict__ w_e2,
    const float* __restrict__ w_n1,  const float* __restrict__ w_n2,
    ushort_t* __restrict__ dst)
{
    __shared__ ushort_t tile[32][264];
    const int wid = blockIdx.x >> 3;   // 0..6
    const int kb  = blockIdx.x & 7;
    const float* src;
    switch (wid) {
        case 0: src = w_in1; break;
        case 1: src = w_in2; break;
        case 2: src = w_e1; break;              // top half (send side)
        case 3: src = w_e1 + 65536; break;      // bottom half (recv side)
        case 4: src = w_e2; break;
        case 5: src = w_n1; break;
        default: src = w_n2; break;
    }
    const int t = threadIdx.x;
#pragma unroll
    for (int k0 = 0; k0 < 32; k0++)
        tile[k0][t] = f2bf(src[(size_t)(kb * 32 + k0) * 256 + t]);  // coalesced
    __syncthreads();
    ushort_t* base = dst + wid * 65536 + kb * 8192 + t * 32;
    const int sw = (t >> 1) & 3;
#pragma unroll
    for (int kc = 0; kc < 4; kc++) {
        union { uint4 q; ushort_t u[8]; } w;
#pragma unroll
        for (int ko = 0; ko < 8; ko++) w.u[ko] = tile[kc * 8 + ko][t];
        *(uint4*)&base[(kc ^ sw) * 8] = w.q;
    }
}

// x fp32 -> bf16
__global__ __launch_bounds__(256) void conv_x(
    const float* __restrict__ x, ushort_t* __restrict__ xb, int n8)
{
    int i = blockIdx.x * 256 + threadIdx.x;
    if (i >= n8) return;
    const float4* p = (const float4*)x + (size_t)i * 2;
    float4 a = p[0], b = p[1];
    ushort4 o0 = make_ushort4(f2bf(a.x), f2bf(a.y), f2bf(a.z), f2bf(a.w));
    ushort4 o1 = make_ushort4(f2bf(b.x), f2bf(b.y), f2bf(b.z), f2bf(b.w));
    ((ushort4*)xb)[(size_t)i * 2]     = o0;
    ((ushort4*)xb)[(size_t)i * 2 + 1] = o1;
}

// ---------------------------------------------------------------------------
// Fused MLP chain (R8). Block = 32 rows, 4 waves (wave owns a 64-col slice).
// A-tiles [32][256] bf16 in LDS, XOR chunk swizzle: elem off =
//   r*256 + ((kc ^ (r&7))*8) + (k&7), kc = k>>3.
// Swapped MFMA: acc = mfma(Wfrag, Xfrag) -> D[row=n (reg), col=m (lane&15)],
// so each lane holds 4 k-contiguous outputs -> b64 LDS writes for handoff.

__device__ __forceinline__ void layer_to_lds(
    const ushort_t* __restrict__ wimg, const float* __restrict__ bias,
    const ushort_t* __restrict__ As, ushort_t* __restrict__ Ad,
    const int w, const int lr, const int lg)
{
    int boffs[4]; float4 b4[4];
#pragma unroll
    for (int fn = 0; fn < 4; fn++) {
        const int n = w * 64 + fn * 16 + lr;
        boffs[fn] = n * 32 + ((lg ^ ((n >> 1) & 3)) * 8);
        b4[fn] = *(const float4*)&bias[w * 64 + fn * 16 + lg * 4];
    }
    bf16x8 bc[4];
#pragma unroll
    for (int fn = 0; fn < 4; fn++) bc[fn] = *(const bf16x8*)&wimg[boffs[fn]];
    f32x4 acc[4][2] = {};
#pragma unroll
    for (int kb = 0; kb < 8; kb++) {
        bf16x8 bn[4];
        if (kb < 7)
#pragma unroll
            for (int fn = 0; fn < 4; fn++)
                bn[fn] = *(const bf16x8*)&wimg[(kb + 1) * 8192 + boffs[fn]];
        bf16x8 af[2];
#pragma unroll
        for (int fm = 0; fm < 2; fm++) {
            const int r = fm * 16 + lr;
            af[fm] = *(const bf16x8*)&As[r * 256 + (((kb * 4 + lg) ^ (r & 7)) * 8)];
        }
#pragma unroll
        for (int fn = 0; fn < 4; fn++)
#pragma unroll
            for (int fm = 0; fm < 2; fm++)
                acc[fn][fm] = __builtin_amdgcn_mfma_f32_16x16x32_bf16(
                    bc[fn], af[fm], acc[fn][fm], 0, 0, 0);
        if (kb < 7)
#pragma unroll
            for (int fn = 0; fn < 4; fn++) bc[fn] = bn[fn];
    }
#pragma unroll
    for (int fn = 0; fn < 4; fn++) {
        const int k0 = w * 64 + fn * 16 + lg * 4;     // output col = next-layer k
        const int kc = k0 >> 3, kj = k0 & 7;
#pragma unroll
        for (int fm = 0; fm < 2; fm++) {
            const int m = fm * 16 + lr;
            float v0 = fmaxf(acc[fn][fm][0] + b4[fn].x, 0.f);
            float v1 = fmaxf(acc[fn][fm][1] + b4[fn].y, 0.f);
            float v2 = fmaxf(acc[fn][fm][2] + b4[fn].z, 0.f);
            float v3 = fmaxf(acc[fn][fm][3] + b4[fn].w, 0.f);
            uint2 q = { cvt_pk_bf16(v0, v1), cvt_pk_bf16(v2, v3) };
            *(uint2*)&Ad[m * 256 + ((kc ^ (m & 7)) * 8) + kj] = q;
        }
    }
}

__device__ __forceinline__ void layer_e1(
    const ushort_t* __restrict__ wE, const float* __restrict__ bE,
    const ushort_t* __restrict__ As, ushort_t* __restrict__ UVb,
    const int m0, const int w, const int lr, const int lg)
{
    const ushort_t* wimg = (w < 2) ? wE : (wE + 65536);
    const int nb = (w & 1) * 128;
    int boffs[8]; float4 b4[8];
#pragma unroll
    for (int fn = 0; fn < 8; fn++) {
        const int n = nb + fn * 16 + lr;
        boffs[fn] = n * 32 + ((lg ^ ((n >> 1) & 3)) * 8);
        if (w < 2) b4[fn] = *(const float4*)&bE[nb + fn * 16 + lg * 4];
        else       b4[fn] = make_float4(0.f, 0.f, 0.f, 0.f);
    }
    bf16x8 bc[8];
#pragma unroll
    for (int fn = 0; fn < 8; fn++) bc[fn] = *(const bf16x8*)&wimg[boffs[fn]];
    f32x4 acc[8][2] = {};
#pragma unroll
    for (int kb = 0; kb < 8; kb++) {
        bf16x8 bn[8];
        if (kb < 7)
#pragma unroll
            for (int fn = 0; fn < 8; fn++)
                bn[fn] = *(const bf16x8*)&wimg[(kb + 1) * 8192 + boffs[fn]];
        bf16x8 af[2];
#pragma unroll
        for (int fm = 0; fm < 2; fm++) {
            const int r = fm * 16 + lr;
            af[fm] = *(const bf16x8*)&As[r * 256 + (((kb * 4 + lg) ^ (r & 7)) * 8)];
        }
#pragma unroll
        for (int fn = 0; fn < 8; fn++)
#pragma unroll
            for (int fm = 0; fm < 2; fm++)
                acc[fn][fm] = __builtin_amdgcn_mfma_f32_16x16x32_bf16(
                    bc[fn], af[fm], acc[fn][fm], 0, 0, 0);
        if (kb < 7)
#pragma unroll
            for (int fn = 0; fn < 8; fn++) bc[fn] = bn[fn];
    }
#pragma unroll
    for (int fn = 0; fn < 8; fn++) {
        const int nglob = w * 128 + fn * 16 + lg * 4;
#pragma unroll
        for (int fm = 0; fm < 2; fm++) {
            const int node = m0 + fm * 16 + lr;
            float v0 = acc[fn][fm][0] + b4[fn].x;
            float v1 = acc[fn][fm][1] + b4[fn].y;
            float v2 = acc[fn][fm][2] + b4[fn].z;
            float v3 = acc[fn][fm][3] + b4[fn].w;
            uint2 q = { cvt_pk_bf16(v0, v1), cvt_pk_bf16(v2, v3) };
            *(uint2*)&UVb[(size_t)node * 512 + nglob] = q;
        }
    }
}

__device__ __forceinline__ void layer_fin(
    const ushort_t* __restrict__ wimg, const float* __restrict__ bias,
    const ushort_t* __restrict__ As, float* __restrict__ out,
    const int m0, const int w, const int lr, const int lg)
{
    int boffs[4]; float4 b4[4];
#pragma unroll
    for (int fn = 0; fn < 4; fn++) {
        const int n = w * 64 + fn * 16 + lr;
        boffs[fn] = n * 32 + ((lg ^ ((n >> 1) & 3)) * 8);
        b4[fn] = *(const float4*)&bias[w * 64 + fn * 16 + lg * 4];
    }
    bf16x8 bc[4];
#pragma unroll
    for (int fn = 0; fn < 4; fn++) bc[fn] = *(const bf16x8*)&wimg[boffs[fn]];
    f32x4 acc[4][2] = {};
#pragma unroll
    for (int kb = 0; kb < 8; kb++) {
        bf16x8 bn[4];
        if (kb < 7)
#pragma unroll
            for (int fn = 0; fn < 4; fn++)
                bn[fn] = *(const bf16x8*)&wimg[(kb + 1) * 8192 + boffs[fn]];
        bf16x8 af[2];
#pragma unroll
        for (int fm = 0; fm < 2; fm++) {
            const int r = fm * 16 + lr;
            af[fm] = *(const bf16x8*)&As[r * 256 + (((kb * 4 + lg) ^ (r & 7)) * 8)];
        }
#pragma unroll
        for (int fn = 0; fn < 4; fn++)
#pragma unroll
            for (int fm = 0; fm < 2; fm++)
                acc[fn][fm] = __builtin_amdgcn_mfma_f32_16x16x32_bf16(
                    bc[fn], af[fm], acc[fn][fm], 0, 0, 0);
        if (kb < 7)
#pragma unroll
            for (int fn = 0; fn < 4; fn++) bc[fn] = bn[fn];
    }
#pragma unroll
    for (int fn = 0; fn < 4; fn++) {
        const int col = w * 64 + fn * 16 + lg * 4;
#pragma unroll
        for (int fm = 0; fm < 2; fm++) {
            const int row = m0 + fm * 16 + lr;
            float4 o;
            o.x = fmaxf(acc[fn][fm][0] + b4[fn].x, 0.f);
            o.y = fmaxf(acc[fn][fm][1] + b4[fn].y, 0.f);
            o.z = fmaxf(acc[fn][fm][2] + b4[fn].z, 0.f);
            o.w = fmaxf(acc[fn][fm][3] + b4[fn].w, 0.f);
            *(float4*)&out[(size_t)row * 256 + col] = o;
        }
    }
}

template <int THREE>
__global__ __launch_bounds__(256, 2) void mlp_chain(
    const ushort_t* __restrict__ in,
    const ushort_t* __restrict__ wA, const float* __restrict__ bA,
    const ushort_t* __restrict__ wB, const float* __restrict__ bB,
    const ushort_t* __restrict__ wE, const float* __restrict__ bE,
    void* __restrict__ out)
{
    __shared__ ushort_t A0[32 * 256];
    __shared__ ushort_t A1[32 * 256];
    const int m0 = blockIdx.x * 32;
    const int t = threadIdx.x;
    const int lane = t & 63, w = t >> 6;
    const int lr = lane & 15, lg = lane >> 4;

#pragma unroll
    for (int i = 0; i < 4; i++) {
        const int r = i * 8 + (t >> 5);
        const int p = t & 31;
        gload16(in + (size_t)(m0 + r) * 256 + ((p ^ (r & 7)) * 8), &A0[i * 2048 + t * 8]);
    }
    __syncthreads();

    layer_to_lds(wA, bA, A0, A1, w, lr, lg);
    __syncthreads();
    if constexpr (THREE) {
        layer_to_lds(wB, bB, A1, A0, w, lr, lg);
        __syncthreads();
        layer_e1(wE, bE, A0, (ushort_t*)out, m0, w, lr, lg);
    } else {
        layer_fin(wB, bB, A1, (float*)out, m0, w, lr, lg);
    }
}

// ---------------------------------------------------------------------------
// Fused edge layer-2 + scatter-mean, v10: BK=64 (4 barrier-steps).
// Grid 2048 x 256 thr (4 waves). Block = (batch, quad of 4 receivers):
// 128 virtual rows (4 recv x 32 slots, slot31 dummy) x N=256.
// Wave w owns cols [w*64, w*64+64): wave tile 128x64, acc[8][4].
// A tile [128][64] bf16, chunk-swizzled: off = r*64 + ((c ^ (r&7))*8) + (k&7),
// c = (k>>3) in 0..7. dbuf 2x16KB. B-frags from L2-resident swizzled image,
// loaded for step kb+1 right after step kb's MFMA streak (covered by build).
__global__ __launch_bounds__(256, 2) void edge_fused(
    const ushort_t* __restrict__ UVb,   // [8192][512] bf16: U'(+b_e1) | V
    const ushort_t* __restrict__ WBsw,  // swizzled w_e2 image
    const float* __restrict__ b2,
    ushort_t* __restrict__ agg)         // [8192][256] bf16
{
    __shared__ ushort_t As[2][128 * 64];   // 16KB each

    const int logical = (blockIdx.x & 7) * 256 + (blockIdx.x >> 3);  // 2048%8==0
    const int bb = logical >> 3;        // batch
    const int g0 = (logical & 7) * 4;   // first receiver of the quad
    const int t = threadIdx.x;
    const int lane = t & 63;
    const int w = t >> 6;
    const int lr = lane & 15, lg = lane >> 4;

    // ---- A-build mapping: thread -> (row, k-half of 32). 2 threads per row.
    const int brow = t >> 1;            // 0..127
    const int kh = t & 1;               // which 32-k half of the 64-k tile
    const int jr = brow >> 5;           // receiver within quad
    const int s = brow & 31;            // slot
    const int j = g0 + jr;
    const int si = (s == 31) ? j : (s + (s >= j ? 1 : 0));
    const ushort_t* up = UVb + (size_t)(bb * 32 + si) * 512 + kh * 32;
    const ushort_t* vp = UVb + (size_t)(bb * 32 + j) * 512 + 256 + kh * 32;
    const int rs7 = brow & 7;
    int aw[4];
#pragma unroll
    for (int i = 0; i < 4; i++)
        aw[i] = brow * 64 + (((kh * 4 + i) ^ rs7) * 8);

    // ---- MFMA-side offsets: af addr = m*1024 + lr*64 + (c^(lr&7))*8, c=ks*4+lg
    const int acof0 = ((lg ^ (lr & 7)) * 8) + lr * 64;   // ks=0 base (+m*1024)
    // ks=1: XOR chunk bit 2 -> elem offset ^ 32
    const int bbase = (w * 64 + lr) * 32 + ((lg ^ ((lr >> 1) & 3)) * 8);  // + fn*512

    // ---- build helper: 32 elems (4 chunks) from u/v uint4[4]
    auto build = [&](int buf, const uint4* u, const uint4* v) {
#pragma unroll
        for (int i = 0; i < 4; i++) {
            uint4 q;
            q.x = cvt_pk_bf16(fmaxf(lo16f(u[i].x) + lo16f(v[i].x), 0.f),
                              fmaxf(hi16f(u[i].x) + hi16f(v[i].x), 0.f));
            q.y = cvt_pk_bf16(fmaxf(lo16f(u[i].y) + lo16f(v[i].y), 0.f),
                              fmaxf(hi16f(u[i].y) + hi16f(v[i].y), 0.f));
            q.z = cvt_pk_bf16(fmaxf(lo16f(u[i].z) + lo16f(v[i].z), 0.f),
                              fmaxf(hi16f(u[i].z) + hi16f(v[i].z), 0.f));
            q.w = cvt_pk_bf16(fmaxf(lo16f(u[i].w) + lo16f(v[i].w), 0.f),
                              fmaxf(hi16f(u[i].w) + hi16f(v[i].w), 0.f));
            *(uint4*)&As[buf][aw[i]] = q;
        }
    };

    // ---- prologue: build tile 0, load B for step 0
    {
        uint4 u[4], v[4];
#pragma unroll
        for (int i = 0; i < 4; i++) {
            u[i] = *(const uint4*)(up + i * 8);
            v[i] = *(const uint4*)(vp + i * 8);
        }
        build(0, u, v);
    }
    bf16x8 bc[2][4];
#pragma unroll
    for (int ks = 0; ks < 2; ks++)
#pragma unroll
        for (int fn = 0; fn < 4; fn++)
            bc[ks][fn] = *(const bf16x8*)&WBsw[ks * 8192 + bbase + fn * 512];

    f32x4 acc[8][4] = {};

#pragma unroll
    for (int kb = 0; kb < 4; kb++) {
        __syncthreads();                      // As[kb&1] ready
        // issue u/v loads for next build (arrive under the MFMA streak)
        uint4 u[4], v[4];
        if (kb < 3) {
            const ushort_t* upn = up + (kb + 1) * 64;
            const ushort_t* vpn = vp + (kb + 1) * 64;
#pragma unroll
            for (int i = 0; i < 4; i++) {
                u[i] = *(const uint4*)(upn + i * 8);
                v[i] = *(const uint4*)(vpn + i * 8);
            }
        }
        // ---- 64-MFMA streak
        __builtin_amdgcn_s_setprio(1);
#pragma unroll
        for (int ks = 0; ks < 2; ks++) {
            bf16x8 af[8];
#pragma unroll
            for (int m = 0; m < 8; m++)
                af[m] = *(const bf16x8*)&As[kb & 1][m * 1024 + (acof0 ^ (ks * 32))];
#pragma unroll
            for (int fn = 0; fn < 4; fn++)
#pragma unroll
                for (int m = 0; m < 8; m++)
                    acc[m][fn] = __builtin_amdgcn_mfma_f32_16x16x32_bf16(
                        af[m], bc[ks][fn], acc[m][fn], 0, 0, 0);
        }
        __builtin_amdgcn_s_setprio(0);
        if (kb < 3) {
            // issue next-step B loads (latency covered by build + barrier)
#pragma unroll
            for (int ks = 0; ks < 2; ks++)
#pragma unroll
                for (int fn = 0; fn < 4; fn++)
                    bc[ks][fn] = *(const bf16x8*)&WBsw[((kb + 1) * 2 + ks) * 8192
                                                       + bbase + fn * 512];
            // build next tile (u/v arrived under the streak)
            build((kb + 1) & 1, u, v);
        }
    }

    // ---- Epilogue: bias+relu, sum 31 real slots per receiver, /31, bf16 out.
#pragma unroll
    for (int fn = 0; fn < 4; fn++) {
        const int col = w * 64 + fn * 16 + lr;
        const float bvf = b2[col];
#pragma unroll
        for (int recv = 0; recv < 4; recv++) {
            float sum = 0.f;
#pragma unroll
            for (int q = 0; q < 2; q++) {
                const int fm = recv * 2 + q;
#pragma unroll
                for (int r = 0; r < 4; r++) {
                    float v = fmaxf(acc[fm][fn][r] + bvf, 0.f);
                    if (!(q == 1 && lg == 3 && r == 3)) sum += v;  // skip slot 31
                }
            }
            sum += __shfl_xor(sum, 16);
            sum += __shfl_xor(sum, 32);
            if (lane < 16)
                agg[(size_t)(bb * 32 + g0 + recv) * 256 + col] = f2bf(sum * (1.0f / 31.0f));
        }
    }
}

// ---------------------------------------------------------------------------
extern "C" void kernel_launch(void* const* d_in, const int* in_sizes, int n_in,
                              void* d_out, int out_size, void* d_ws, size_t ws_size,
                              hipStream_t stream)
{
    const float* x     = (const float*)d_in[0];
    const float* w_in1 = (const float*)d_in[3];
    const float* b_in1 = (const float*)d_in[4];
    const float* w_in2 = (const float*)d_in[5];
    const float* b_in2 = (const float*)d_in[6];
    const float* w_e1  = (const float*)d_in[7];
    const float* b_e1  = (const float*)d_in[8];
    const float* w_e2  = (const float*)d_in[9];
    const float* b_e2  = (const float*)d_in[10];
    const float* w_n1  = (const float*)d_in[11];
    const float* b_n1  = (const float*)d_in[12];
    const float* w_n2  = (const float*)d_in[13];
    const float* b_n2  = (const float*)d_in[14];

    char* ws = (char*)d_ws;
    size_t off = 0;
    auto alloc = [&](size_t n) { char* p = ws + off; off += (n + 255) & ~(size_t)255; return p; };

    ushort_t* wt  = (ushort_t*)alloc(7 * 65536 * sizeof(ushort_t));
    ushort_t* xb  = (ushort_t*)alloc(8192 * 256 * 2);
    ushort_t* UVb = (ushort_t*)alloc(8192 * 512 * 2);
    ushort_t* ag  = (ushort_t*)alloc(8192 * 256 * 2);
    (void)ws_size; (void)in_sizes; (void)n_in; (void)out_size;

    prep_weights<<<56, 256, 0, stream>>>(w_in1, w_in2, w_e1, w_e2, w_n1, w_n2, wt);
    conv_x<<<1024, 256, 0, stream>>>(x, xb, 262144);

    // pass 0 front: in1 -> in2 -> e1
    mlp_chain<1><<<256, 256, 0, stream>>>(xb,
        wt + 0 * 65536, b_in1, wt + 1 * 65536, b_in2, wt + 2 * 65536, b_e1, UVb);
    edge_fused<<<2048, 256, 0, stream>>>(UVb, wt + 4 * 65536, b_e2, ag);
    // pass 1 front: n1 -> n2 -> e1
    mlp_chain<1><<<256, 256, 0, stream>>>(ag,
        wt + 5 * 65536, b_n1, wt + 6 * 65536, b_n2, wt + 2 * 65536, b_e1, UVb);
    edge_fused<<<2048, 256, 0, stream>>>(UVb, wt + 4 * 65536, b_e2, ag);
    // final: n1 -> n2 (f32 out)
    mlp_chain<0><<<256, 256, 0, stream>>>(ag,
        wt + 5 * 65536, b_n1, wt + 6 * 65536, b_n2, nullptr, nullptr, d_out);
}